// Round 13
// baseline (72.882 us; speedup 1.0000x reference)
//
#include <hip/hip_runtime.h>
#include <hip/hip_bf16.h>

#define D 128            // EMBED_DIM
#define G 3              // NUM_GROUPS
#define BN 128           // dst nodes per bucket (7 bits in record)
#define CH 4096          // edges per bin chunk
#define BIN_T 512        // threads per bin block (8 edges/thread)
#define CAP 4096         // max records for LDS sort path (mean 2048)
#define REG 8192         // fixed-stride region per bucket in temp (hard cap)

__device__ __forceinline__ float b2f(unsigned short u) {
    return __uint_as_float((unsigned int)u << 16);
}

// ---------------------------------------------------------------------------
// Kernel 1: per-node linear(128->3) + softmax -> coeff (float4), bf16 X copy.
// Block 0 additionally zeroes cursor[] (stream-ordered before lg_bin).
// ---------------------------------------------------------------------------
__global__ __launch_bounds__(256) void lg_coeff_kernel(
        const float* __restrict__ X, const float* __restrict__ W,
        const float* __restrict__ b, float4* __restrict__ coeff,
        __hip_bfloat16* __restrict__ Xh,          // may be null (fallback)
        int* __restrict__ cursor, int nbuck,      // may be null (fallback)
        int n) {
    if (cursor && blockIdx.x == 0) {
        for (int i = threadIdx.x; i < nbuck; i += 256) cursor[i] = 0;
    }
    int node = (int)((blockIdx.x * (size_t)blockDim.x + threadIdx.x) >> 6);
    int lane = threadIdx.x & 63;
    if (node >= n) return;
    float2 x = ((const float2*)(X + (size_t)node * D))[lane];
    if (Xh) {
        __hip_bfloat162 h2;
        h2.x = __float2bfloat16(x.x);
        h2.y = __float2bfloat16(x.y);
        ((__hip_bfloat162*)(Xh + (size_t)node * D))[lane] = h2;
    }
    int d0 = lane * 2;
    float s0 = x.x * W[d0 * G + 0] + x.y * W[(d0 + 1) * G + 0];
    float s1 = x.x * W[d0 * G + 1] + x.y * W[(d0 + 1) * G + 1];
    float s2 = x.x * W[d0 * G + 2] + x.y * W[(d0 + 1) * G + 2];
    #pragma unroll
    for (int off = 32; off; off >>= 1) {
        s0 += __shfl_xor(s0, off);
        s1 += __shfl_xor(s1, off);
        s2 += __shfl_xor(s2, off);
    }
    s0 += b[0]; s1 += b[1]; s2 += b[2];     // T = 1.0
    float m = fmaxf(s0, fmaxf(s1, s2));
    float e0 = __expf(s0 - m), e1 = __expf(s1 - m), e2 = __expf(s2 - m);
    float inv = 1.0f / (e0 + e1 + e2);
    if (lane == 0) coeff[node] = make_float4(e0 * inv, e1 * inv, e2 * inv, 0.0f);
}

// ---------------------------------------------------------------------------
// Kernel 2: LDS-staged bucket binning into FIXED-STRIDE regions.
// rec(u32) = src(16) | dst_low7 << 16. 512 threads, CH=4096 edges in
// registers (196 blocks -> better CU spread than 98). Wave-0 shfl scan.
// histogram -> scan -> LDS scatter -> bulk-reserve (final cursor = count)
// -> coalesced burst flush to temp[bk*REG..]. Writes clamped to REG.
// Requires n <= 65536, nbuck <= 512.
// ---------------------------------------------------------------------------
__global__ __launch_bounds__(BIN_T) void lg_bin_kernel(
        const int* __restrict__ src, const int* __restrict__ dst,
        int* __restrict__ cursor, unsigned int* __restrict__ temp,
        int E, int nbuck) {
    __shared__ unsigned int stage[CH];                     // 16 KB
    __shared__ int hist[512], hbase[512], hcnt[512], gbs[512];
    int tid = threadIdx.x;
    int wv = tid >> 6, ln = tid & 63;
    int e0 = blockIdx.x * CH;
    int ecnt = min(CH, E - e0);
    for (int i = tid; i < 512; i += BIN_T) { hist[i] = 0; hcnt[i] = 0; }
    __syncthreads();
    // load edges to registers (coalesced, once) + histogram
    int rs[CH / BIN_T], rd[CH / BIN_T];
    #pragma unroll
    for (int u = 0; u < CH / BIN_T; ++u) {
        int k = tid + u * BIN_T;
        if (k < ecnt) {
            rs[u] = src[e0 + k];
            rd[u] = dst[e0 + k];
            atomicAdd(&hist[rd[u] >> 7], 1);
        } else rd[u] = -1;
    }
    __syncthreads();
    // wave-0 shfl exclusive scan over 512 entries (8 per lane)
    if (wv == 0) {
        int c[8]; int tot = 0;
        #pragma unroll
        for (int t = 0; t < 8; ++t) { c[t] = hist[ln * 8 + t]; tot += c[t]; }
        int s = tot;
        #pragma unroll
        for (int o = 1; o < 64; o <<= 1) {
            int y = __shfl_up(s, o);
            if (ln >= o) s += y;
        }
        int run = s - tot;
        #pragma unroll
        for (int t = 0; t < 8; ++t) { hbase[ln * 8 + t] = run; run += c[t]; }
    }
    __syncthreads();
    // scatter into stage from registers
    #pragma unroll
    for (int u = 0; u < CH / BIN_T; ++u) {
        if (rd[u] >= 0) {
            int bk = rd[u] >> 7;
            int idx = hbase[bk] + atomicAdd(&hcnt[bk], 1);
            stage[idx] = ((unsigned int)rs[u] & 0xFFFFu) |
                         (((unsigned int)rd[u] & 127u) << 16);
        }
    }
    // bulk-reserve region slots (one atomic per non-empty bucket)
    for (int i = tid; i < nbuck; i += BIN_T) {
        int c = hist[i];
        gbs[i] = c ? atomicAdd(&cursor[i], c) : 0;
    }
    __syncthreads();   // covers scatter + reserve
    // coalesced burst flush into fixed-stride region (clamped: no corruption)
    for (int bk = wv; bk < nbuck; bk += BIN_T / 64) {
        int c = hist[bk];
        if (!c) continue;
        int gb = gbs[bk], hb = hbase[bk];
        unsigned int* rg = temp + (size_t)bk * REG;
        int lim = min(c, REG - gb);               // region hard cap
        for (int j = ln; j < lim; j += 64) rg[gb + j] = stage[hb + j];
    }
}

// ---------------------------------------------------------------------------
// Kernel 3: per-bucket sort + register-accumulate aggregation.
// One 1024-thread block (16 waves) per bucket; count from cursor[bk];
// records at temp[bk*REG..]. Internal per-node histogram (uint4 record
// loads) + wave-0 shfl scan, counting-sort into LDS, then per-node
// accumulation with PAIRED 2-row gathers: lanes 0-31 gather row A, lanes
// 32-63 row B, 8B/lane (4 bf16 dims). Halves gather instructions; one
// shfl_xor(32) reduce; lanes 0-31 store float4 rows.
// ---------------------------------------------------------------------------
__global__ __launch_bounds__(1024) void lg_sortagg_kernel(
        const __hip_bfloat16* __restrict__ Xh,
        const float4* __restrict__ coeff,
        const unsigned int* __restrict__ temp,
        const int* __restrict__ cursor,
        float* __restrict__ out, int n) {
    __shared__ unsigned int stage[CAP];    // 16 KB
    __shared__ float4 cdl[BN];             // 2 KB: dst coeffs
    __shared__ int nhist[BN], nbase[BN], ncur[BN];
    int tid = threadIdx.x;
    int wv = tid >> 6, ln = tid & 63;
    int nb0 = blockIdx.x * BN;
    int nv = min(BN, n - nb0);
    const unsigned int* rg = temp + (size_t)blockIdx.x * REG;
    int count = min(cursor[blockIdx.x], REG);
    if (tid < BN) { nhist[tid] = 0; ncur[tid] = 0; }
    if (tid < nv) cdl[tid] = coeff[nb0 + tid];
    __syncthreads();

    if (count <= CAP) {
        // ---- load records (uint4, coalesced) + per-node histogram ----
        int base = tid * 4;
        unsigned int r0 = 0, r1 = 0, r2 = 0, r3 = 0;
        if (base + 3 < count) {
            uint4 R = *(const uint4*)(rg + base);
            r0 = R.x; r1 = R.y; r2 = R.z; r3 = R.w;
            atomicAdd(&nhist[(r0 >> 16) & 127u], 1);
            atomicAdd(&nhist[(r1 >> 16) & 127u], 1);
            atomicAdd(&nhist[(r2 >> 16) & 127u], 1);
            atomicAdd(&nhist[(r3 >> 16) & 127u], 1);
        } else {
            if (base + 0 < count) { r0 = rg[base + 0]; atomicAdd(&nhist[(r0 >> 16) & 127u], 1); }
            if (base + 1 < count) { r1 = rg[base + 1]; atomicAdd(&nhist[(r1 >> 16) & 127u], 1); }
            if (base + 2 < count) { r2 = rg[base + 2]; atomicAdd(&nhist[(r2 >> 16) & 127u], 1); }
            if (base + 3 < count) { r3 = rg[base + 3]; atomicAdd(&nhist[(r3 >> 16) & 127u], 1); }
        }
        __syncthreads();
        // ---- wave-0 shfl exclusive scan over 128 node counts (2/lane) ----
        if (wv == 0) {
            int a = nhist[2 * ln], b2 = nhist[2 * ln + 1];
            int tot = a + b2;
            int s = tot;
            #pragma unroll
            for (int o = 1; o < 64; o <<= 1) {
                int y = __shfl_up(s, o);
                if (ln >= o) s += y;
            }
            int excl = s - tot;
            nbase[2 * ln] = excl;
            nbase[2 * ln + 1] = excl + a;
        }
        __syncthreads();
        // ---- compute w + counting-sort into stage ----
        auto place = [&](unsigned int rec) {
            int s = (int)(rec & 0xFFFFu);
            int d = (int)((rec >> 16) & 127u);
            float4 cs = coeff[s];
            float4 cd = cdl[d];
            float w = cs.x * cd.x + cs.y * cd.y + cs.z * cd.z;
            unsigned int wb = __float_as_uint(w);
            wb += 0x7FFFu + ((wb >> 16) & 1u);       // RNE to bf16
            int pos = nbase[d] + atomicAdd(&ncur[d], 1);
            stage[pos] = (rec & 0xFFFFu) | (wb & 0xFFFF0000u);
        };
        if (base + 0 < count) place(r0);
        if (base + 1 < count) place(r1);
        if (base + 2 < count) place(r2);
        if (base + 3 < count) place(r3);
        __syncthreads();
        // ---- per-node accumulation, paired 2-row gathers ----
        int sub = ln & 31;           // lane covers bf16 dims sub*4 .. sub*4+3
        bool hiHalf = (ln >= 32);
        for (int i = wv; i < nv; i += 16) {
            int ibeg = nbase[i];
            int icnt = nhist[i];
            float4 acc = make_float4(0.0f, 0.0f, 0.0f, 0.0f);
            int j = 0;
            for (; j + 3 < icnt; j += 4) {
                unsigned int a0 = stage[ibeg + j + 0];
                unsigned int a1 = stage[ibeg + j + 1];
                unsigned int b0 = stage[ibeg + j + 2];
                unsigned int b1 = stage[ibeg + j + 3];
                unsigned int qa = hiHalf ? a1 : a0;
                unsigned int qb = hiHalf ? b1 : b0;
                float wa = __uint_as_float(qa & 0xFFFF0000u);
                float wb = __uint_as_float(qb & 0xFFFF0000u);
                ushort4 ha = ((const ushort4*)(Xh + (size_t)(qa & 0xFFFFu) * D))[sub];
                ushort4 hb = ((const ushort4*)(Xh + (size_t)(qb & 0xFFFFu) * D))[sub];
                acc.x = fmaf(wa, b2f(ha.x), acc.x);
                acc.y = fmaf(wa, b2f(ha.y), acc.y);
                acc.z = fmaf(wa, b2f(ha.z), acc.z);
                acc.w = fmaf(wa, b2f(ha.w), acc.w);
                acc.x = fmaf(wb, b2f(hb.x), acc.x);
                acc.y = fmaf(wb, b2f(hb.y), acc.y);
                acc.z = fmaf(wb, b2f(hb.z), acc.z);
                acc.w = fmaf(wb, b2f(hb.w), acc.w);
            }
            for (; j < icnt; j += 2) {
                unsigned int a0 = stage[ibeg + j];
                // phantom partner: same src, w-bits zeroed -> FMA no-op
                unsigned int a1 = (j + 1 < icnt) ? stage[ibeg + j + 1]
                                                 : (a0 & 0xFFFFu);
                unsigned int qa = hiHalf ? a1 : a0;
                float wa = __uint_as_float(qa & 0xFFFF0000u);
                ushort4 ha = ((const ushort4*)(Xh + (size_t)(qa & 0xFFFFu) * D))[sub];
                acc.x = fmaf(wa, b2f(ha.x), acc.x);
                acc.y = fmaf(wa, b2f(ha.y), acc.y);
                acc.z = fmaf(wa, b2f(ha.z), acc.z);
                acc.w = fmaf(wa, b2f(ha.w), acc.w);
            }
            // cross-half reduce: lane l += lane l^32
            acc.x += __shfl_xor(acc.x, 32);
            acc.y += __shfl_xor(acc.y, 32);
            acc.z += __shfl_xor(acc.z, 32);
            acc.w += __shfl_xor(acc.w, 32);
            float invd = 1.0f / fmaxf((float)icnt, 1.0f);
            if (!hiHalf)
                ((float4*)(out + (size_t)(nb0 + i) * D))[sub] =
                    make_float4(acc.x * invd, acc.y * invd,
                                acc.z * invd, acc.w * invd);
        }
    } else {
        // ---- rare overflow path (CAP < count <= REG): ballot scan ----
        for (int k = tid; k < count; k += 1024)
            atomicAdd(&nhist[(rg[k] >> 16) & 127u], 1);
        __syncthreads();
        for (int i = wv; i < nv; i += 16) {
            float4 cd = cdl[i];
            float accx = 0.0f, accy = 0.0f;
            for (int bb = 0; bb < count; bb += 64) {
                int k = bb + ln;
                unsigned int rec = (k < count) ? rg[k] : 0u;
                bool ok = (k < count) && ((int)((rec >> 16) & 127u) == i);
                unsigned long long mask = __ballot(ok);
                while (mask) {
                    int bpos = __ffsll((long long)mask) - 1;
                    mask &= mask - 1;
                    unsigned int rr = __shfl(rec, bpos);
                    int s0 = (int)(rr & 0xFFFFu);
                    float4 cs = coeff[s0];
                    float w = cs.x * cd.x + cs.y * cd.y + cs.z * cd.z;
                    __hip_bfloat162 h0 = ((const __hip_bfloat162*)(Xh + (size_t)s0 * D))[ln];
                    accx = fmaf(w, __bfloat162float(h0.x), accx);
                    accy = fmaf(w, __bfloat162float(h0.y), accy);
                }
            }
            float invd = 1.0f / fmaxf((float)nhist[i], 1.0f);
            ((float2*)(out + (size_t)(nb0 + i) * D))[ln] =
                make_float2(accx * invd, accy * invd);
        }
    }
}

// ---------------------------------------------------------------------------
// Minimal-workspace / large-n fallback: float-atomic scatter
// ---------------------------------------------------------------------------
__global__ void lg_deg_kernel(const int* __restrict__ dst, int* __restrict__ deg, int E) {
    int e = (int)(blockIdx.x * (size_t)blockDim.x + threadIdx.x);
    if (e < E) atomicAdd(&deg[dst[e]], 1);
}

__global__ void lg_scatter_kernel(const float* __restrict__ X,
                                  const float4* __restrict__ coeff,
                                  const int* __restrict__ src, const int* __restrict__ dst,
                                  float* __restrict__ out, int E) {
    int e = (int)((blockIdx.x * (size_t)blockDim.x + threadIdx.x) >> 6);
    int lane = threadIdx.x & 63;
    if (e >= E) return;
    int s = src[e], d = dst[e];
    float4 cs = coeff[s], cd = coeff[d];
    float se = cs.x * cd.x + cs.y * cd.y + cs.z * cd.z;
    float2 x = ((const float2*)(X + (size_t)s * D))[lane];
    atomicAdd(&out[(size_t)d * D + lane * 2 + 0], se * x.x);
    atomicAdd(&out[(size_t)d * D + lane * 2 + 1], se * x.y);
}

__global__ void lg_scale_kernel(float* __restrict__ out, const int* __restrict__ deg, int n) {
    int node = (int)((blockIdx.x * (size_t)blockDim.x + threadIdx.x) >> 6);
    int lane = threadIdx.x & 63;
    if (node >= n) return;
    float invd = 1.0f / fmaxf((float)deg[node], 1.0f);
    float2* p = (float2*)(out + (size_t)node * D);
    float2 v = p[lane];
    p[lane] = make_float2(v.x * invd, v.y * invd);
}

extern "C" void kernel_launch(void* const* d_in, const int* in_sizes, int n_in,
                              void* d_out, int out_size, void* d_ws, size_t ws_size,
                              hipStream_t stream) {
    const float* X   = (const float*)d_in[0];
    const int*   src = (const int*)d_in[1];
    const int*   dst = (const int*)d_in[2];
    const float* W   = (const float*)d_in[3];
    const float* b   = (const float*)d_in[4];
    float* out = (float*)d_out;
    int n = in_sizes[0] / D;
    int E = in_sizes[1];

    int nbuck  = (n + BN - 1) / BN;      // dst buckets
    int nchunk = (E + CH - 1) / CH;      // edge chunks

    char* ws = (char*)d_ws;
    size_t p = 0;
    auto alloc = [&](size_t bytes) -> void* {
        void* r = ws + p;
        p = (p + bytes + 255) & ~(size_t)255;
        return r;
    };
    float4* coeff  = (float4*)alloc((size_t)n * sizeof(float4));
    int*    cursor = (int*)alloc((size_t)nbuck * sizeof(int));
    unsigned int* temp = (unsigned int*)alloc((size_t)nbuck * REG * sizeof(unsigned int));
    __hip_bfloat16* Xh = (__hip_bfloat16*)alloc((size_t)n * D * sizeof(__hip_bfloat16));
    size_t p_full = p;
    int*    deg    = (int*)alloc((size_t)n * sizeof(int));   // fallback only

    int node_blocks = (n + 3) / 4;      // 4 waves (nodes) per 256-thread block
    int edge_blocks = (E + 255) / 256;

    bool fast_ok = (n <= 65536) && (nbuck <= 512) && (p_full <= ws_size);
    if (fast_ok) {
        lg_coeff_kernel<<<node_blocks, 256, 0, stream>>>(X, W, b, coeff, Xh,
                                                         cursor, nbuck, n);
        lg_bin_kernel<<<nchunk, BIN_T, 0, stream>>>(src, dst, cursor, temp, E, nbuck);
        lg_sortagg_kernel<<<nbuck, 1024, 0, stream>>>(Xh, coeff, temp, cursor, out, n);
    } else {
        // fallback: coeff + deg; atomic scatter
        hipMemsetAsync(deg, 0, (size_t)n * sizeof(int), stream);
        hipMemsetAsync(out, 0, (size_t)n * D * sizeof(float), stream);
        lg_coeff_kernel<<<node_blocks, 256, 0, stream>>>(X, W, b, coeff, nullptr,
                                                         nullptr, 0, n);
        lg_deg_kernel<<<edge_blocks, 256, 0, stream>>>(dst, deg, E);
        lg_scatter_kernel<<<(E + 3) / 4, 256, 0, stream>>>(X, coeff, src, dst, out, E);
        lg_scale_kernel<<<node_blocks, 256, 0, stream>>>(out, deg, n);
    }
}

// Round 14
// 62.115 us; speedup vs baseline: 1.1734x; 1.1734x over previous
//
#include <hip/hip_runtime.h>
#include <hip/hip_bf16.h>

#define D 128            // EMBED_DIM
#define G 3              // NUM_GROUPS
#define BN 128           // dst nodes per bucket (7 bits in record)
#define CH 8192          // edges per bin chunk
#define BIN_T 1024       // threads per bin block (8 edges/thread in registers)
#define CAP 4096         // max records for LDS sort path (mean 2048)
#define REG 8192         // fixed-stride region per bucket in temp (hard cap)

__device__ __forceinline__ float b2f(unsigned short u) {
    return __uint_as_float((unsigned int)u << 16);
}

// ---------------------------------------------------------------------------
// Kernel 1: per-node linear(128->3) + softmax -> coeff (float4), bf16 X copy.
// Block 0 additionally zeroes cursor[] (stream-ordered before lg_bin).
// ---------------------------------------------------------------------------
__global__ __launch_bounds__(256) void lg_coeff_kernel(
        const float* __restrict__ X, const float* __restrict__ W,
        const float* __restrict__ b, float4* __restrict__ coeff,
        __hip_bfloat16* __restrict__ Xh,          // may be null (fallback)
        int* __restrict__ cursor, int nbuck,      // may be null (fallback)
        int n) {
    if (cursor && blockIdx.x == 0) {
        for (int i = threadIdx.x; i < nbuck; i += 256) cursor[i] = 0;
    }
    int node = (int)((blockIdx.x * (size_t)blockDim.x + threadIdx.x) >> 6);
    int lane = threadIdx.x & 63;
    if (node >= n) return;
    float2 x = ((const float2*)(X + (size_t)node * D))[lane];
    if (Xh) {
        __hip_bfloat162 h2;
        h2.x = __float2bfloat16(x.x);
        h2.y = __float2bfloat16(x.y);
        ((__hip_bfloat162*)(Xh + (size_t)node * D))[lane] = h2;
    }
    int d0 = lane * 2;
    float s0 = x.x * W[d0 * G + 0] + x.y * W[(d0 + 1) * G + 0];
    float s1 = x.x * W[d0 * G + 1] + x.y * W[(d0 + 1) * G + 1];
    float s2 = x.x * W[d0 * G + 2] + x.y * W[(d0 + 1) * G + 2];
    #pragma unroll
    for (int off = 32; off; off >>= 1) {
        s0 += __shfl_xor(s0, off);
        s1 += __shfl_xor(s1, off);
        s2 += __shfl_xor(s2, off);
    }
    s0 += b[0]; s1 += b[1]; s2 += b[2];     // T = 1.0
    float m = fmaxf(s0, fmaxf(s1, s2));
    float e0 = __expf(s0 - m), e1 = __expf(s1 - m), e2 = __expf(s2 - m);
    float inv = 1.0f / (e0 + e1 + e2);
    if (lane == 0) coeff[node] = make_float4(e0 * inv, e1 * inv, e2 * inv, 0.0f);
}

// ---------------------------------------------------------------------------
// Kernel 2: LDS-staged bucket binning into FIXED-STRIDE regions.
// rec(u32) = src(16) | dst_low7 << 16. 1024 threads, CH=8192 edges in
// registers. Wave-0 shfl scan. Scatter records per-entry bucket id into
// stage_bk so the FLUSH is fully thread-parallel: stage is bucket-sorted,
// so consecutive threads write consecutive temp addresses (no serial
// per-wave bucket loop). Writes clamped to REG. n <= 65536, nbuck <= 512.
// ---------------------------------------------------------------------------
__global__ __launch_bounds__(BIN_T) void lg_bin_kernel(
        const int* __restrict__ src, const int* __restrict__ dst,
        int* __restrict__ cursor, unsigned int* __restrict__ temp,
        int E, int nbuck) {
    __shared__ unsigned int stage[CH];                     // 32 KB
    __shared__ unsigned short stage_bk[CH];                // 16 KB
    __shared__ int hist[512], hbase[512], hcnt[512], gbs[512];
    int tid = threadIdx.x;
    int wv = tid >> 6, ln = tid & 63;
    int e0 = blockIdx.x * CH;
    int ecnt = min(CH, E - e0);
    for (int i = tid; i < 512; i += BIN_T) { hist[i] = 0; hcnt[i] = 0; }
    __syncthreads();
    // load edges to registers (coalesced, once) + histogram
    int rs[CH / BIN_T], rd[CH / BIN_T];
    #pragma unroll
    for (int u = 0; u < CH / BIN_T; ++u) {
        int k = tid + u * BIN_T;
        if (k < ecnt) {
            rs[u] = src[e0 + k];
            rd[u] = dst[e0 + k];
            atomicAdd(&hist[rd[u] >> 7], 1);
        } else rd[u] = -1;
    }
    __syncthreads();
    // wave-0 shfl exclusive scan over 512 entries (8 per lane)
    if (wv == 0) {
        int c[8]; int tot = 0;
        #pragma unroll
        for (int t = 0; t < 8; ++t) { c[t] = hist[ln * 8 + t]; tot += c[t]; }
        int s = tot;
        #pragma unroll
        for (int o = 1; o < 64; o <<= 1) {
            int y = __shfl_up(s, o);
            if (ln >= o) s += y;
        }
        int run = s - tot;
        #pragma unroll
        for (int t = 0; t < 8; ++t) { hbase[ln * 8 + t] = run; run += c[t]; }
    }
    __syncthreads();
    // scatter into stage from registers (+ bucket id per entry)
    #pragma unroll
    for (int u = 0; u < CH / BIN_T; ++u) {
        if (rd[u] >= 0) {
            int bk = rd[u] >> 7;
            int idx = hbase[bk] + atomicAdd(&hcnt[bk], 1);
            stage[idx] = ((unsigned int)rs[u] & 0xFFFFu) |
                         (((unsigned int)rd[u] & 127u) << 16);
            stage_bk[idx] = (unsigned short)bk;
        }
    }
    // bulk-reserve region slots (one atomic per non-empty bucket)
    for (int i = tid; i < nbuck; i += BIN_T) {
        int c = hist[i];
        gbs[i] = c ? atomicAdd(&cursor[i], c) : 0;
    }
    __syncthreads();   // covers scatter + reserve
    // fully parallel flush: entry k goes to temp[bk*REG + gbs[bk] + local]
    // (stage is bucket-sorted -> consecutive threads hit consecutive addrs)
    for (int k = tid; k < ecnt; k += BIN_T) {
        int bk = stage_bk[k];
        int pos = gbs[bk] + (k - hbase[bk]);
        if (pos < REG) temp[(size_t)bk * REG + pos] = stage[k];
    }
}

// ---------------------------------------------------------------------------
// Kernel 3: per-bucket sort + register-accumulate aggregation.
// One 1024-thread block (16 waves) per bucket; count from cursor[bk];
// records at temp[bk*REG..]. Internal per-node histogram (uint4 record
// loads) + wave-0 shfl scan, counting-sort into LDS, then per-node
// accumulation with PAIRED 2-row gathers: lanes 0-31 gather row A, lanes
// 32-63 row B, 8B/lane (4 bf16 dims). One shfl_xor(32) reduce; lanes 0-31
// store float4 rows (coalesced).
// ---------------------------------------------------------------------------
__global__ __launch_bounds__(1024) void lg_sortagg_kernel(
        const __hip_bfloat16* __restrict__ Xh,
        const float4* __restrict__ coeff,
        const unsigned int* __restrict__ temp,
        const int* __restrict__ cursor,
        float* __restrict__ out, int n) {
    __shared__ unsigned int stage[CAP];    // 16 KB
    __shared__ float4 cdl[BN];             // 2 KB: dst coeffs
    __shared__ int nhist[BN], nbase[BN], ncur[BN];
    int tid = threadIdx.x;
    int wv = tid >> 6, ln = tid & 63;
    int nb0 = blockIdx.x * BN;
    int nv = min(BN, n - nb0);
    const unsigned int* rg = temp + (size_t)blockIdx.x * REG;
    int count = min(cursor[blockIdx.x], REG);
    if (tid < BN) { nhist[tid] = 0; ncur[tid] = 0; }
    if (tid < nv) cdl[tid] = coeff[nb0 + tid];
    __syncthreads();

    if (count <= CAP) {
        // ---- load records (uint4, coalesced) + per-node histogram ----
        int base = tid * 4;
        unsigned int r0 = 0, r1 = 0, r2 = 0, r3 = 0;
        if (base + 3 < count) {
            uint4 R = *(const uint4*)(rg + base);
            r0 = R.x; r1 = R.y; r2 = R.z; r3 = R.w;
            atomicAdd(&nhist[(r0 >> 16) & 127u], 1);
            atomicAdd(&nhist[(r1 >> 16) & 127u], 1);
            atomicAdd(&nhist[(r2 >> 16) & 127u], 1);
            atomicAdd(&nhist[(r3 >> 16) & 127u], 1);
        } else {
            if (base + 0 < count) { r0 = rg[base + 0]; atomicAdd(&nhist[(r0 >> 16) & 127u], 1); }
            if (base + 1 < count) { r1 = rg[base + 1]; atomicAdd(&nhist[(r1 >> 16) & 127u], 1); }
            if (base + 2 < count) { r2 = rg[base + 2]; atomicAdd(&nhist[(r2 >> 16) & 127u], 1); }
            if (base + 3 < count) { r3 = rg[base + 3]; atomicAdd(&nhist[(r3 >> 16) & 127u], 1); }
        }
        __syncthreads();
        // ---- wave-0 shfl exclusive scan over 128 node counts (2/lane) ----
        if (wv == 0) {
            int a = nhist[2 * ln], b2 = nhist[2 * ln + 1];
            int tot = a + b2;
            int s = tot;
            #pragma unroll
            for (int o = 1; o < 64; o <<= 1) {
                int y = __shfl_up(s, o);
                if (ln >= o) s += y;
            }
            int excl = s - tot;
            nbase[2 * ln] = excl;
            nbase[2 * ln + 1] = excl + a;
        }
        __syncthreads();
        // ---- compute w + counting-sort into stage ----
        auto place = [&](unsigned int rec) {
            int s = (int)(rec & 0xFFFFu);
            int d = (int)((rec >> 16) & 127u);
            float4 cs = coeff[s];
            float4 cd = cdl[d];
            float w = cs.x * cd.x + cs.y * cd.y + cs.z * cd.z;
            unsigned int wb = __float_as_uint(w);
            wb += 0x7FFFu + ((wb >> 16) & 1u);       // RNE to bf16
            int pos = nbase[d] + atomicAdd(&ncur[d], 1);
            stage[pos] = (rec & 0xFFFFu) | (wb & 0xFFFF0000u);
        };
        if (base + 0 < count) place(r0);
        if (base + 1 < count) place(r1);
        if (base + 2 < count) place(r2);
        if (base + 3 < count) place(r3);
        __syncthreads();
        // ---- per-node accumulation, paired 2-row gathers ----
        int sub = ln & 31;           // lane covers bf16 dims sub*4 .. sub*4+3
        bool hiHalf = (ln >= 32);
        for (int i = wv; i < nv; i += 16) {
            int ibeg = nbase[i];
            int icnt = nhist[i];
            float4 acc = make_float4(0.0f, 0.0f, 0.0f, 0.0f);
            int j = 0;
            for (; j + 3 < icnt; j += 4) {
                unsigned int a0 = stage[ibeg + j + 0];
                unsigned int a1 = stage[ibeg + j + 1];
                unsigned int b0 = stage[ibeg + j + 2];
                unsigned int b1 = stage[ibeg + j + 3];
                unsigned int qa = hiHalf ? a1 : a0;
                unsigned int qb = hiHalf ? b1 : b0;
                float wa = __uint_as_float(qa & 0xFFFF0000u);
                float wb = __uint_as_float(qb & 0xFFFF0000u);
                ushort4 ha = ((const ushort4*)(Xh + (size_t)(qa & 0xFFFFu) * D))[sub];
                ushort4 hb = ((const ushort4*)(Xh + (size_t)(qb & 0xFFFFu) * D))[sub];
                acc.x = fmaf(wa, b2f(ha.x), acc.x);
                acc.y = fmaf(wa, b2f(ha.y), acc.y);
                acc.z = fmaf(wa, b2f(ha.z), acc.z);
                acc.w = fmaf(wa, b2f(ha.w), acc.w);
                acc.x = fmaf(wb, b2f(hb.x), acc.x);
                acc.y = fmaf(wb, b2f(hb.y), acc.y);
                acc.z = fmaf(wb, b2f(hb.z), acc.z);
                acc.w = fmaf(wb, b2f(hb.w), acc.w);
            }
            for (; j < icnt; j += 2) {
                unsigned int a0 = stage[ibeg + j];
                // phantom partner: same src, w-bits zeroed -> FMA no-op
                unsigned int a1 = (j + 1 < icnt) ? stage[ibeg + j + 1]
                                                 : (a0 & 0xFFFFu);
                unsigned int qa = hiHalf ? a1 : a0;
                float wa = __uint_as_float(qa & 0xFFFF0000u);
                ushort4 ha = ((const ushort4*)(Xh + (size_t)(qa & 0xFFFFu) * D))[sub];
                acc.x = fmaf(wa, b2f(ha.x), acc.x);
                acc.y = fmaf(wa, b2f(ha.y), acc.y);
                acc.z = fmaf(wa, b2f(ha.z), acc.z);
                acc.w = fmaf(wa, b2f(ha.w), acc.w);
            }
            // cross-half reduce: lane l += lane l^32
            acc.x += __shfl_xor(acc.x, 32);
            acc.y += __shfl_xor(acc.y, 32);
            acc.z += __shfl_xor(acc.z, 32);
            acc.w += __shfl_xor(acc.w, 32);
            float invd = 1.0f / fmaxf((float)icnt, 1.0f);
            if (!hiHalf)
                ((float4*)(out + (size_t)(nb0 + i) * D))[sub] =
                    make_float4(acc.x * invd, acc.y * invd,
                                acc.z * invd, acc.w * invd);
        }
    } else {
        // ---- rare overflow path (CAP < count <= REG): ballot scan ----
        for (int k = tid; k < count; k += 1024)
            atomicAdd(&nhist[(rg[k] >> 16) & 127u], 1);
        __syncthreads();
        for (int i = wv; i < nv; i += 16) {
            float4 cd = cdl[i];
            float accx = 0.0f, accy = 0.0f;
            for (int bb = 0; bb < count; bb += 64) {
                int k = bb + ln;
                unsigned int rec = (k < count) ? rg[k] : 0u;
                bool ok = (k < count) && ((int)((rec >> 16) & 127u) == i);
                unsigned long long mask = __ballot(ok);
                while (mask) {
                    int bpos = __ffsll((long long)mask) - 1;
                    mask &= mask - 1;
                    unsigned int rr = __shfl(rec, bpos);
                    int s0 = (int)(rr & 0xFFFFu);
                    float4 cs = coeff[s0];
                    float w = cs.x * cd.x + cs.y * cd.y + cs.z * cd.z;
                    __hip_bfloat162 h0 = ((const __hip_bfloat162*)(Xh + (size_t)s0 * D))[ln];
                    accx = fmaf(w, __bfloat162float(h0.x), accx);
                    accy = fmaf(w, __bfloat162float(h0.y), accy);
                }
            }
            float invd = 1.0f / fmaxf((float)nhist[i], 1.0f);
            ((float2*)(out + (size_t)(nb0 + i) * D))[ln] =
                make_float2(accx * invd, accy * invd);
        }
    }
}

// ---------------------------------------------------------------------------
// Minimal-workspace / large-n fallback: float-atomic scatter
// ---------------------------------------------------------------------------
__global__ void lg_deg_kernel(const int* __restrict__ dst, int* __restrict__ deg, int E) {
    int e = (int)(blockIdx.x * (size_t)blockDim.x + threadIdx.x);
    if (e < E) atomicAdd(&deg[dst[e]], 1);
}

__global__ void lg_scatter_kernel(const float* __restrict__ X,
                                  const float4* __restrict__ coeff,
                                  const int* __restrict__ src, const int* __restrict__ dst,
                                  float* __restrict__ out, int E) {
    int e = (int)((blockIdx.x * (size_t)blockDim.x + threadIdx.x) >> 6);
    int lane = threadIdx.x & 63;
    if (e >= E) return;
    int s = src[e], d = dst[e];
    float4 cs = coeff[s], cd = coeff[d];
    float se = cs.x * cd.x + cs.y * cd.y + cs.z * cd.z;
    float2 x = ((const float2*)(X + (size_t)s * D))[lane];
    atomicAdd(&out[(size_t)d * D + lane * 2 + 0], se * x.x);
    atomicAdd(&out[(size_t)d * D + lane * 2 + 1], se * x.y);
}

__global__ void lg_scale_kernel(float* __restrict__ out, const int* __restrict__ deg, int n) {
    int node = (int)((blockIdx.x * (size_t)blockDim.x + threadIdx.x) >> 6);
    int lane = threadIdx.x & 63;
    if (node >= n) return;
    float invd = 1.0f / fmaxf((float)deg[node], 1.0f);
    float2* p = (float2*)(out + (size_t)node * D);
    float2 v = p[lane];
    p[lane] = make_float2(v.x * invd, v.y * invd);
}

extern "C" void kernel_launch(void* const* d_in, const int* in_sizes, int n_in,
                              void* d_out, int out_size, void* d_ws, size_t ws_size,
                              hipStream_t stream) {
    const float* X   = (const float*)d_in[0];
    const int*   src = (const int*)d_in[1];
    const int*   dst = (const int*)d_in[2];
    const float* W   = (const float*)d_in[3];
    const float* b   = (const float*)d_in[4];
    float* out = (float*)d_out;
    int n = in_sizes[0] / D;
    int E = in_sizes[1];

    int nbuck  = (n + BN - 1) / BN;      // dst buckets
    int nchunk = (E + CH - 1) / CH;      // edge chunks

    char* ws = (char*)d_ws;
    size_t p = 0;
    auto alloc = [&](size_t bytes) -> void* {
        void* r = ws + p;
        p = (p + bytes + 255) & ~(size_t)255;
        return r;
    };
    float4* coeff  = (float4*)alloc((size_t)n * sizeof(float4));
    int*    cursor = (int*)alloc((size_t)nbuck * sizeof(int));
    unsigned int* temp = (unsigned int*)alloc((size_t)nbuck * REG * sizeof(unsigned int));
    __hip_bfloat16* Xh = (__hip_bfloat16*)alloc((size_t)n * D * sizeof(__hip_bfloat16));
    size_t p_full = p;
    int*    deg    = (int*)alloc((size_t)n * sizeof(int));   // fallback only

    int node_blocks = (n + 3) / 4;      // 4 waves (nodes) per 256-thread block
    int edge_blocks = (E + 255) / 256;

    bool fast_ok = (n <= 65536) && (nbuck <= 512) && (p_full <= ws_size);
    if (fast_ok) {
        lg_coeff_kernel<<<node_blocks, 256, 0, stream>>>(X, W, b, coeff, Xh,
                                                         cursor, nbuck, n);
        lg_bin_kernel<<<nchunk, BIN_T, 0, stream>>>(src, dst, cursor, temp, E, nbuck);
        lg_sortagg_kernel<<<nbuck, 1024, 0, stream>>>(Xh, coeff, temp, cursor, out, n);
    } else {
        // fallback: coeff + deg; atomic scatter
        hipMemsetAsync(deg, 0, (size_t)n * sizeof(int), stream);
        hipMemsetAsync(out, 0, (size_t)n * D * sizeof(float), stream);
        lg_coeff_kernel<<<node_blocks, 256, 0, stream>>>(X, W, b, coeff, nullptr,
                                                         nullptr, 0, n);
        lg_deg_kernel<<<edge_blocks, 256, 0, stream>>>(dst, deg, E);
        lg_scatter_kernel<<<(E + 3) / 4, 256, 0, stream>>>(X, coeff, src, dst, out, E);
        lg_scale_kernel<<<node_blocks, 256, 0, stream>>>(out, deg, n);
    }
}